// Round 3
// baseline (337.707 us; speedup 1.0000x reference)
//
#include <hip/hip_runtime.h>
#include <math.h>

#define EPSV 1e-5f

typedef __attribute__((ext_vector_type(8))) short short8;
typedef __attribute__((ext_vector_type(4))) float f32x4;

// pack two f32 -> two bf16 (RTNE) in one uint
static __device__ __forceinline__ unsigned bfpack2(float lo, float hi) {
    union { float f; unsigned u; } a, b;
    a.f = lo; b.f = hi;
    unsigned ua = a.u + 0x7fffu + ((a.u >> 16) & 1u);
    unsigned ub = b.u + 0x7fffu + ((b.u >> 16) & 1u);
    return (ua >> 16) | (ub & 0xffff0000u);
}

// ---------------------------------------------------------------------------
// K1 gram: G[b] = X_b^T X_b via bf16 MFMA, symmetric 3-tile scheme per batch.
// Software-prefetched: chunk kc+1's global loads issue before chunk kc's MFMAs.
// ---------------------------------------------------------------------------
__global__ __launch_bounds__(256) void gram(
    const float* __restrict__ Xx, const float* __restrict__ Xz,
    float* __restrict__ Gx, float* __restrict__ Gz,
    float* __restrict__ csx, float* __restrict__ csz)
{
    __shared__ __align__(16) unsigned short AT[128 * 72];
    __shared__ __align__(16) unsigned short BT[128 * 72];
    __shared__ float csr[8 * 128];
    int id = blockIdx.x;
    const float* X; float* G; float* cs; int P;
    if (id < 192) { X = Xx; G = Gx; cs = csx; P = 1024; }
    else { id -= 192; X = Xz; G = Gz; cs = csz; P = 256; }
    const int b = id & 63;
    const int tile = id >> 6;            // 0:(0,0) 1:(1,1) 2:(0,1)
    const int ci = (tile == 1) ? 1 : 0;
    const int cj = (tile == 0) ? 0 : 1;
    const bool diag = (tile < 2);
    const int nk = P >> 6;
    const int t = threadIdx.x;
    const int cq = (t & 31) * 4;
    const int ph = t >> 5;
    const float* Xb = X + (long)b * P * 256;

    const int w = t >> 6;
    const int wr = w >> 1, wc = w & 1;
    const int quad = (t >> 4) & 3, lane16 = t & 15;

    f32x4 acc[4][4] = {};
    float csA[4] = {0.f, 0.f, 0.f, 0.f};

    float4 va[8], vb[8];
    {
        const int p0 = ph * 8;
#pragma unroll
        for (int k = 0; k < 8; ++k)
            va[k] = *(const float4*)(Xb + (long)(p0 + k) * 256 + ci * 128 + cq);
        if (!diag) {
#pragma unroll
            for (int k = 0; k < 8; ++k)
                vb[k] = *(const float4*)(Xb + (long)(p0 + k) * 256 + cj * 128 + cq);
        }
    }

    for (int kc = 0; kc < nk; ++kc) {
        __syncthreads();   // previous chunk's MFMA reads done
#pragma unroll
        for (int j = 0; j < 4; ++j) {
            uint4 pk;
            pk.x = bfpack2(((const float*)&va[0])[j], ((const float*)&va[1])[j]);
            pk.y = bfpack2(((const float*)&va[2])[j], ((const float*)&va[3])[j]);
            pk.z = bfpack2(((const float*)&va[4])[j], ((const float*)&va[5])[j]);
            pk.w = bfpack2(((const float*)&va[6])[j], ((const float*)&va[7])[j]);
            *(uint4*)&AT[(cq + j) * 72 + ph * 8] = pk;
            if (diag) {
                csA[j] += ((const float*)&va[0])[j] + ((const float*)&va[1])[j]
                        + ((const float*)&va[2])[j] + ((const float*)&va[3])[j]
                        + ((const float*)&va[4])[j] + ((const float*)&va[5])[j]
                        + ((const float*)&va[6])[j] + ((const float*)&va[7])[j];
            }
        }
        if (!diag) {
#pragma unroll
            for (int j = 0; j < 4; ++j) {
                uint4 pk;
                pk.x = bfpack2(((const float*)&vb[0])[j], ((const float*)&vb[1])[j]);
                pk.y = bfpack2(((const float*)&vb[2])[j], ((const float*)&vb[3])[j]);
                pk.z = bfpack2(((const float*)&vb[4])[j], ((const float*)&vb[5])[j]);
                pk.w = bfpack2(((const float*)&vb[6])[j], ((const float*)&vb[7])[j]);
                *(uint4*)&BT[(cq + j) * 72 + ph * 8] = pk;
            }
        }
        __syncthreads();
        if (kc + 1 < nk) {   // prefetch next chunk (overlaps MFMAs below)
            const int p0 = (kc + 1) * 64 + ph * 8;
#pragma unroll
            for (int k = 0; k < 8; ++k)
                va[k] = *(const float4*)(Xb + (long)(p0 + k) * 256 + ci * 128 + cq);
            if (!diag) {
#pragma unroll
                for (int k = 0; k < 8; ++k)
                    vb[k] = *(const float4*)(Xb + (long)(p0 + k) * 256 + cj * 128 + cq);
            }
        }
        const unsigned short* Br = diag ? AT : BT;
#pragma unroll
        for (int ks = 0; ks < 2; ++ks) {
            const int ko = ks * 32 + quad * 8;
            short8 bfrag[4];
#pragma unroll
            for (int ni = 0; ni < 4; ++ni)
                bfrag[ni] = *(const short8*)&Br[(wc * 64 + ni * 16 + lane16) * 72 + ko];
#pragma unroll
            for (int mi = 0; mi < 4; ++mi) {
                short8 afrag = *(const short8*)&AT[(wr * 64 + mi * 16 + lane16) * 72 + ko];
#pragma unroll
                for (int ni = 0; ni < 4; ++ni)
                    acc[mi][ni] = __builtin_amdgcn_mfma_f32_16x16x32_bf16(afrag, bfrag[ni], acc[mi][ni], 0, 0, 0);
            }
        }
    }
#pragma unroll
    for (int mi = 0; mi < 4; ++mi) {
        const int rbase = ci * 128 + wr * 64 + mi * 16 + quad * 4;
#pragma unroll
        for (int ni = 0; ni < 4; ++ni) {
            const int col = cj * 128 + wc * 64 + ni * 16 + lane16;
#pragma unroll
            for (int r = 0; r < 4; ++r) {
                G[((long)(b * 256 + rbase + r)) * 256 + col] = acc[mi][ni][r];
                if (!diag)
                    G[((long)(b * 256 + col)) * 256 + rbase + r] = acc[mi][ni][r];
            }
        }
    }
    if (diag) {
#pragma unroll
        for (int j = 0; j < 4; ++j) csr[ph * 128 + cq + j] = csA[j];
        __syncthreads();
        if (t < 128) {
            float s = 0.f;
#pragma unroll
            for (int k = 0; k < 8; ++k) s += csr[k * 128 + t];
            cs[b * 256 + ci * 128 + t] = s;
        }
    }
}

// ---------------------------------------------------------------------------
// K2 megamid: one block per batch. proj-x -> kxr(LDS); proj-z -> kern slices
// -> dy (regs); depth+point (point -> global, L2); lntem; buildM -> MT, svec.
// All phase bodies verbatim from the previously verified kernels; only the
// storage location (LDS instead of global) changes.
// ---------------------------------------------------------------------------
__global__ __launch_bounds__(256) void megamid(
    const float* __restrict__ Gx, const float* __restrict__ csx,
    const float* __restrict__ Wx, const float* __restrict__ bx,
    const float* __restrict__ Gz, const float* __restrict__ csz,
    const float* __restrict__ Wz, const float* __restrict__ bz,
    const float* __restrict__ Wdyn, const float* __restrict__ bdyn,
    const float* __restrict__ g_norm, const float* __restrict__ b_norm,
    const float* __restrict__ Wp, const float* __restrict__ bp,
    float* __restrict__ point, unsigned short* __restrict__ MT,
    float* __restrict__ svec)
{
    __shared__ __align__(16) unsigned char pool[149760];
    float* KXR          = (float*)pool;                          // [64][261] f32  (kxr, persists to dp)
    unsigned short* ATW = (unsigned short*)(pool + 66816);       // [64][264] ush  (W^T bf16)
    unsigned short* BTC = (unsigned short*)(pool + 100608);      // [64][72] ush
    float* SLICE        = (float*)(pool + 109824);               // [64 c][72] kern slice (c-major)
    float* WC2          = (float*)(pool + 128256);               // [64 c][68 m] Wdyn chunk
    float* WD3L         = (float*)(pool + 145664);               // [192]
    float* DYB          = (float*)(pool + 66816);                // [64 n][68]   (aliases ATW, later)
    float* WPT          = (float*)(pool + 84224);                // [64 m][68 n]
    float* DEP          = (float*)(pool + 101632);               // [64 m][68]
    float* WD3S         = (float*)(pool + 119040);               // [256]
    float* RS           = (float*)(pool + 120064);               // [3*1088]
    float* SRA          = (float*)(pool + 101632);               // [256] (lntem, aliases DEP)
    float* SRB          = (float*)(pool + 102656);               // [256]
    float* WNV          = (float*)(pool + 103680);               // [64]
    float* TOT          = (float*)(pool + 103936);               // [4]
    float* KS           = (float*)(pool + 66816);                // [64][68] (buildM, aliases DYB)
    float* WT           = (float*)(pool + 84224);                // [64][68] (aliases WPT)
    float* PSUM         = (float*)(pool + 146432);               // [192] persists
    float* MURR         = (float*)(pool + 147200);               // [128] persists
    float* ABL          = (float*)(pool + 147712);               // [512] persists

    const int b = blockIdx.x;
    const int t = threadIdx.x;
    const int w = t >> 6, quad = (t >> 4) & 3, lane16 = t & 15;
    const int tr = t >> 4, tc = t & 15;
    const int nwd3 = t / 3, jwd3 = t - nwd3 * 3;

    if (t < 192) PSUM[t] = 0.f;

    // dy accumulators (persist across the z ct-loop)
    float adv[4][4];
#pragma unroll
    for (int j = 0; j < 4; ++j) {
        float bj = bdyn[3 + tc * 4 + j];
        adv[0][j] = bj; adv[1][j] = bj; adv[2][j] = bj; adv[3][j] = bj;
    }
    float wdacc = 0.f;

    for (int path = 0; path < 2; ++path) {
        const float* G    = path ? Gz : Gx;
        const float* cs   = path ? csz : csx;
        const float* W    = path ? Wz : Wx;
        const float* bias = path ? bz : bx;
        __syncthreads();                    // prior readers of ATW done
        {   // stage W^T -> bf16 (verbatim proj)
            const int n = t & 63, ph2 = t >> 6;
#pragma unroll
            for (int cc = 0; cc < 4; ++cc) {
                float v[16];
#pragma unroll
                for (int k = 0; k < 16; ++k) v[k] = W[(ph2 * 64 + cc * 16 + k) * 64 + n];
                uint4 p0, p1;
                p0.x = bfpack2(v[0], v[1]);   p0.y = bfpack2(v[2], v[3]);
                p0.z = bfpack2(v[4], v[5]);   p0.w = bfpack2(v[6], v[7]);
                p1.x = bfpack2(v[8], v[9]);   p1.y = bfpack2(v[10], v[11]);
                p1.z = bfpack2(v[12], v[13]); p1.w = bfpack2(v[14], v[15]);
                *(uint4*)&ATW[n * 264 + ph2 * 64 + cc * 16]     = p0;
                *(uint4*)&ATW[n * 264 + ph2 * 64 + cc * 16 + 8] = p1;
            }
        }
        __syncthreads();
        for (int ct = 0; ct < 4; ++ct) {
            f32x4 pacc[4] = {{0.f,0.f,0.f,0.f},{0.f,0.f,0.f,0.f},{0.f,0.f,0.f,0.f},{0.f,0.f,0.f,0.f}};
            const int row = t >> 2, cqq = t & 3;
            const float* Grow = G + ((long)(b * 256 + ct * 64 + row)) * 256 + cqq * 16;
            for (int kc = 0; kc < 4; ++kc) {
                float4 g0 = *(const float4*)(Grow + kc * 64 + 0);
                float4 g1 = *(const float4*)(Grow + kc * 64 + 4);
                float4 g2 = *(const float4*)(Grow + kc * 64 + 8);
                float4 g3 = *(const float4*)(Grow + kc * 64 + 12);
                uint4 pk0, pk1;
                pk0.x = bfpack2(g0.x, g0.y); pk0.y = bfpack2(g0.z, g0.w);
                pk0.z = bfpack2(g1.x, g1.y); pk0.w = bfpack2(g1.z, g1.w);
                pk1.x = bfpack2(g2.x, g2.y); pk1.y = bfpack2(g2.z, g2.w);
                pk1.z = bfpack2(g3.x, g3.y); pk1.w = bfpack2(g3.z, g3.w);
                __syncthreads();
                *(uint4*)&BTC[row * 72 + cqq * 16]     = pk0;
                *(uint4*)&BTC[row * 72 + cqq * 16 + 8] = pk1;
                __syncthreads();
#pragma unroll
                for (int ks = 0; ks < 2; ++ks) {
                    const int ko = ks * 32 + quad * 8;
                    short8 bfrag = *(const short8*)&BTC[(w * 16 + lane16) * 72 + ko];
#pragma unroll
                    for (int mi = 0; mi < 4; ++mi) {
                        short8 afrag = *(const short8*)&ATW[(mi * 16 + lane16) * 264 + kc * 64 + ko];
                        pacc[mi] = __builtin_amdgcn_mfma_f32_16x16x32_bf16(afrag, bfrag, pacc[mi], 0, 0, 0);
                    }
                }
            }
            const int col = ct * 64 + w * 16 + lane16;
            const float csv = cs[b * 256 + col];
            if (path == 0) {
                // kxr -> LDS [n][261]
#pragma unroll
                for (int mi = 0; mi < 4; ++mi) {
                    const int nrow = mi * 16 + quad * 4;
#pragma unroll
                    for (int r = 0; r < 4; ++r)
                        KXR[(nrow + r) * 261 + col] = pacc[mi][r] + bias[nrow + r] * csv;
                }
            } else {
                // kern slice -> LDS [c_loc][72][n], then dy-accumulate
                const int cloc = w * 16 + lane16;
#pragma unroll
                for (int mi = 0; mi < 4; ++mi) {
                    const int nrow = mi * 16 + quad * 4;
#pragma unroll
                    for (int r = 0; r < 4; ++r)
                        SLICE[cloc * 72 + nrow + r] = pacc[mi][r] + bias[nrow + r] * csv;
                }
                {   // stage Wdyn chunk (point cols + depth cols)
                    const int m = t & 63, clg = t >> 6;
#pragma unroll
                    for (int j = 0; j < 16; ++j) {
                        int cl = clg * 16 + j;
                        WC2[cl * 68 + m] = Wdyn[((long)(ct * 64 + cl)) * 67 + 3 + m];
                    }
                    if (t < 192) WD3L[t] = Wdyn[((long)(ct * 64 + nwd3)) * 67 + jwd3];
                }
                __syncthreads();
#pragma unroll 16
                for (int cl = 0; cl < 64; ++cl) {
                    float4 a  = *(float4*)&SLICE[cl * 72 + tr * 4];
                    float4 wv = *(float4*)&WC2[cl * 68 + tc * 4];
                    adv[0][0]+=a.x*wv.x; adv[0][1]+=a.x*wv.y; adv[0][2]+=a.x*wv.z; adv[0][3]+=a.x*wv.w;
                    adv[1][0]+=a.y*wv.x; adv[1][1]+=a.y*wv.y; adv[1][2]+=a.y*wv.z; adv[1][3]+=a.y*wv.w;
                    adv[2][0]+=a.z*wv.x; adv[2][1]+=a.z*wv.y; adv[2][2]+=a.z*wv.z; adv[2][3]+=a.z*wv.w;
                    adv[3][0]+=a.w*wv.x; adv[3][1]+=a.w*wv.y; adv[3][2]+=a.w*wv.z; adv[3][3]+=a.w*wv.w;
                }
                if (t < 192) {
#pragma unroll 16
                    for (int cl = 0; cl < 64; ++cl)
                        wdacc += SLICE[cl * 72 + nwd3] * WD3L[cl * 3 + jwd3];
                }
            }
        }
    }
    // ---- dyb to LDS (aliases ATW: all readers done) ----
    __syncthreads();
#pragma unroll
    for (int i = 0; i < 4; ++i) {
        float4 o = make_float4(adv[i][0], adv[i][1], adv[i][2], adv[i][3]);
        *(float4*)&DYB[(tr * 4 + i) * 68 + tc * 4] = o;
    }
    if (t < 192) DYB[nwd3 * 68 + 64 + jwd3] = wdacc + bdyn[jwd3];
    __syncthreads();
    // ---- wpT + wd3 ----
#pragma unroll
    for (int i = 0; i < 4; ++i) {
        int idx = t + i * 256; int n = idx >> 4, m0 = (idx & 15) * 4;
        float4 w4 = *(float4*)&DYB[n * 68 + m0];
        WPT[(m0+0)*68 + n] = w4.x; WPT[(m0+1)*68 + n] = w4.y;
        WPT[(m0+2)*68 + n] = w4.z; WPT[(m0+3)*68 + n] = w4.w;
    }
    if (t < 64) {
        WD3S[t*4+0] = DYB[t*68 + 64]; WD3S[t*4+1] = DYB[t*68 + 65]; WD3S[t*4+2] = DYB[t*68 + 66];
    }
    __syncthreads();
    // ---- depth conv + point GEMM, 4 column tiles ----
    for (int ct = 0; ct < 4; ++ct) {
        const int c0 = ct * 64;
#pragma unroll
        for (int im = 0; im < 4; ++im) {
            int m = tr * 4 + im;
            float w0 = WD3S[m*4+0], w1 = WD3S[m*4+1], w2 = WD3S[m*4+2];
#pragma unroll
            for (int jc = 0; jc < 4; ++jc) {
                int cl = tc * 4 + jc, c = c0 + cl;
                float vm1 = (c > 0)   ? KXR[m * 261 + c - 1] : 0.f;
                float v0  =            KXR[m * 261 + c];
                float vp1 = (c < 255) ? KXR[m * 261 + c + 1] : 0.f;
                DEP[m * 68 + cl] = fmaxf(w0 * vm1 + w1 * v0 + w2 * vp1, 0.f);
            }
        }
        __syncthreads();
        float pa[4][4] = {};
#pragma unroll 16
        for (int m = 0; m < 64; ++m) {
            float4 a4 = *(float4*)&WPT[m * 68 + tr * 4];
            float4 d4 = *(float4*)&DEP[m * 68 + tc * 4];
            pa[0][0]+=a4.x*d4.x; pa[0][1]+=a4.x*d4.y; pa[0][2]+=a4.x*d4.z; pa[0][3]+=a4.x*d4.w;
            pa[1][0]+=a4.y*d4.x; pa[1][1]+=a4.y*d4.y; pa[1][2]+=a4.y*d4.z; pa[1][3]+=a4.y*d4.w;
            pa[2][0]+=a4.z*d4.x; pa[2][1]+=a4.z*d4.y; pa[2][2]+=a4.z*d4.z; pa[2][3]+=a4.z*d4.w;
            pa[3][0]+=a4.w*d4.x; pa[3][1]+=a4.w*d4.y; pa[3][2]+=a4.w*d4.z; pa[3][3]+=a4.w*d4.w;
        }
        int cg = c0 + tc * 4;
        float4 g4  = *(const float4*)(g_norm + cg);
        float4 wp4 = *(const float4*)(Wp + cg);
        float gw0 = g4.x*wp4.x, gw1 = g4.y*wp4.y, gw2 = g4.z*wp4.z, gw3 = g4.w*wp4.w;
#pragma unroll
        for (int i = 0; i < 4; ++i) {
            float4 o = make_float4(pa[i][0], pa[i][1], pa[i][2], pa[i][3]);
            *(float4*)(point + ((long)(b * 64 + tr * 4 + i)) * 256 + cg) = o;
            float s  = o.x + o.y + o.z + o.w;
            float s2 = o.x*o.x + o.y*o.y + o.z*o.z + o.w*o.w;
            float dg = o.x*gw0 + o.y*gw1 + o.z*gw2 + o.w*gw3;
            RS[0*1088 + (tr*4+i)*17 + tc] = s;
            RS[1*1088 + (tr*4+i)*17 + tc] = s2;
            RS[2*1088 + (tr*4+i)*17 + tc] = dg;
        }
        __syncthreads();
        if (t < 64) {
            float s = 0.f, s2 = 0.f, dg = 0.f;
#pragma unroll
            for (int j = 0; j < 16; ++j) {
                s  += RS[t*17 + j];
                s2 += RS[1088 + t*17 + j];
                dg += RS[2176 + t*17 + j];
            }
            PSUM[t] += s; PSUM[64 + t] += s2; PSUM[128 + t] += dg;
        }
        __syncthreads();
    }
    // ---- lntem (verbatim, LDS-fed) ----
    {
        const int c = t;
        float gc = g_norm[c], bc = b_norm[c], wpc = Wp[c];
        SRA[t] = gc * wpc; SRB[t] = bc * wpc;
        __syncthreads();
        for (int off = 128; off >= 1; off >>= 1) {
            if (t < off) { SRA[t] += SRA[t+off]; SRB[t] += SRB[t+off]; }
            __syncthreads();
        }
        if (t == 0) { TOT[0] = SRA[0]; TOT[1] = SRB[0] + bp[0]; }
        __syncthreads();
        float Sgw = TOT[0], Sbw = TOT[1];

        float protoe = 0.f, mu = 0.f, rr = 0.f;
        if (t < 64) {
            float S1 = PSUM[t], S2 = PSUM[64 + t], Sdg = PSUM[128 + t];
            mu = S1 * (1.f / 256.f);
            float var = S2 * (1.f / 256.f) - mu * mu;
            rr = rsqrtf(var + EPSV);
            protoe = rr * (Sdg - mu * Sgw) + Sbw;
            WNV[t] = protoe * rr;
            MURR[2*t] = rr; MURR[2*t + 1] = -mu * rr;
        }
        __syncthreads();
        SRA[t] = (t < 64) ? protoe * rr * mu : 0.f;
        SRB[t] = (t < 64) ? protoe : 0.f;
        __syncthreads();
        for (int off = 128; off >= 1; off >>= 1) {
            if (t < off) { SRA[t] += SRA[t+off]; SRB[t] += SRB[t+off]; }
            __syncthreads();
        }
        if (t == 0) { TOT[2] = SRA[0]; TOT[3] = SRB[0]; }
        __syncthreads();
        float Bv = TOT[2], Sv = TOT[3];

        const float* pcol = point + (long)b * 64 * 256 + c;
        float a0 = 0.f, a1 = 0.f, a2 = 0.f, a3 = 0.f;
#pragma unroll
        for (int n = 0; n < 64; n += 4) {
            a0 += WNV[n+0] * pcol[(n+0) * 256];
            a1 += WNV[n+1] * pcol[(n+1) * 256];
            a2 += WNV[n+2] * pcol[(n+2) * 256];
            a3 += WNV[n+3] * pcol[(n+3) * 256];
        }
        float accA = a0 + a1 + a2 + a3;
        float x = gc * (accA - Bv) + bc * Sv;
        float temv = 1.f / (1.f + expf(-x));
        ABL[c] = gc * temv; ABL[256 + c] = bc * temv;
    }
    // ---- buildM (verbatim, LDS murr/AB) ----
    for (int mt = 0; mt < 4; ++mt) {
        __syncthreads();
        {
            const int n = t >> 2, q = t & 3;
            const float rn = MURR[2 * n], qn = MURR[2 * n + 1];
            const float* prow = point + ((long)(b * 64 + n)) * 256 + mt * 64 + q * 16;
#pragma unroll
            for (int j = 0; j < 4; ++j) {
                float4 p4 = *(const float4*)(prow + j * 4);
                float4 A4 = *(float4*)&ABL[mt * 64 + q * 16 + j * 4];
                float4 B4 = *(float4*)&ABL[256 + mt * 64 + q * 16 + j * 4];
                float4 kv;
                kv.x = (p4.x * rn + qn) * A4.x + B4.x;
                kv.y = (p4.y * rn + qn) * A4.y + B4.y;
                kv.z = (p4.z * rn + qn) * A4.z + B4.z;
                kv.w = (p4.w * rn + qn) * A4.w + B4.w;
                *(float4*)&KS[n * 68 + q * 16 + j * 4] = kv;
            }
        }
        __syncthreads();
        if (t < 64) {
            float sv = 0.f;
#pragma unroll
            for (int n2 = 0; n2 < 64; ++n2) sv += bx[n2] * KS[n2 * 68 + t];
            svec[b * 256 + mt * 64 + t] = sv;
        }
        const int nw = t & 63, ph2 = t >> 6;
        for (int cc = 0; cc < 4; ++cc) {
            float wv[16];
#pragma unroll
            for (int k = 0; k < 16; ++k) wv[k] = Wx[(cc * 64 + ph2 * 16 + k) * 64 + nw];
            __syncthreads();
#pragma unroll
            for (int k = 0; k < 16; ++k) WT[nw * 68 + ph2 * 16 + k] = wv[k];
            __syncthreads();
            float a2[4][4] = {};
#pragma unroll 16
            for (int n2 = 0; n2 < 64; ++n2) {
                float4 a4 = *(float4*)&KS[n2 * 68 + tr * 4];
                float4 w4 = *(float4*)&WT[n2 * 68 + tc * 4];
                a2[0][0]+=a4.x*w4.x; a2[0][1]+=a4.x*w4.y; a2[0][2]+=a4.x*w4.z; a2[0][3]+=a4.x*w4.w;
                a2[1][0]+=a4.y*w4.x; a2[1][1]+=a4.y*w4.y; a2[1][2]+=a4.y*w4.z; a2[1][3]+=a4.y*w4.w;
                a2[2][0]+=a4.z*w4.x; a2[2][1]+=a4.z*w4.y; a2[2][2]+=a4.z*w4.z; a2[2][3]+=a4.z*w4.w;
                a2[3][0]+=a4.w*w4.x; a2[3][1]+=a4.w*w4.y; a2[3][2]+=a4.w*w4.z; a2[3][3]+=a4.w*w4.w;
            }
#pragma unroll
            for (int i = 0; i < 4; ++i) {
                uint2 pk;
                pk.x = bfpack2(a2[i][0], a2[i][1]);
                pk.y = bfpack2(a2[i][2], a2[i][3]);
                *(uint2*)&MT[((long)(b * 256 + mt * 64 + tr * 4 + i)) * 256 + cc * 64 + tc * 4] = pk;
            }
        }
    }
}

// ---------------------------------------------------------------------------
// K3 final2: x_corr = X_b @ M + svec via bf16 MFMA, then row LN + relu +
// residual. 32-row tiles, grid 2048, b=id&63 (XCD affinity). Pack-phase xf
// registers reused as residual (no 2nd read phase); single-pass epilogue
// with conflict-free c = q*4+i*32 mapping; 3 barriers post-MFMA.
// ---------------------------------------------------------------------------
__global__ __launch_bounds__(256) void final2(
    const float* __restrict__ xf, const unsigned short* __restrict__ MT,
    const float* __restrict__ svec, const float* __restrict__ g,
    const float* __restrict__ bt, float* __restrict__ out)
{
    __shared__ __align__(16) float Sl[32 * 260];   // 33280B; XT (bf16) aliases
    __shared__ float red1[128], red2[128];
    __shared__ float muS[32], rrS[32];
    unsigned short* XT = (unsigned short*)Sl;      // [32 p][264 pad] bf16
    const int t = threadIdx.x;
    const int id = blockIdx.x;
    const int b = id & 63, pt = id >> 6;
    const int w = t >> 6, quad = (t >> 4) & 3, lane16 = t & 15;
    const int p = t >> 3, q = t & 7;
    const float* Xb = xf + ((long)(b * 1024 + pt * 32)) * 256;
    float4 xv[8];
#pragma unroll
    for (int i = 0; i < 8; ++i) {
        const int c = q * 4 + i * 32;
        xv[i] = *(const float4*)(Xb + (long)p * 256 + c);
    }
#pragma unroll
    for (int i = 0; i < 8; ++i) {
        const int c = q * 4 + i * 32;
        uint2 pk;
        pk.x = bfpack2(xv[i].x, xv[i].y);
        pk.y = bfpack2(xv[i].z, xv[i].w);
        *(uint2*)&XT[p * 264 + c] = pk;
    }
    __syncthreads();
    f32x4 acc[2][4] = {};
    const unsigned short* Mb = MT + (long)b * 65536;
    for (int ks = 0; ks < 8; ++ks) {
        const int ko = ks * 32 + quad * 8;
        short8 bf4[4], af2[2];
#pragma unroll
        for (int ni = 0; ni < 4; ++ni)
            bf4[ni] = *(const short8*)(Mb + (long)(w * 64 + ni * 16 + lane16) * 256 + ko);
#pragma unroll
        for (int mi = 0; mi < 2; ++mi)
            af2[mi] = *(const short8*)&XT[(mi * 16 + lane16) * 264 + ko];
#pragma unroll
        for (int mi = 0; mi < 2; ++mi)
#pragma unroll
            for (int ni = 0; ni < 4; ++ni)
                acc[mi][ni] = __builtin_amdgcn_mfma_f32_16x16x32_bf16(af2[mi], bf4[ni], acc[mi][ni], 0, 0, 0);
    }
    // add svec, per-row sums
    float sv4[4];
#pragma unroll
    for (int ni = 0; ni < 4; ++ni) sv4[ni] = svec[b * 256 + w * 64 + ni * 16 + lane16];
#pragma unroll
    for (int mi = 0; mi < 2; ++mi)
#pragma unroll
        for (int r = 0; r < 4; ++r) {
            float s1 = 0.f, s2 = 0.f;
#pragma unroll
            for (int ni = 0; ni < 4; ++ni) {
                float v2 = acc[mi][ni][r] + sv4[ni];
                acc[mi][ni][r] = v2;
                s1 += v2; s2 += v2 * v2;
            }
#pragma unroll
            for (int m = 1; m <= 8; m <<= 1) {
                s1 += __shfl_xor(s1, m);
                s2 += __shfl_xor(s2, m);
            }
            if (lane16 == 0) {
                red1[(mi * 16 + quad * 4 + r) * 4 + w] = s1;
                red2[(mi * 16 + quad * 4 + r) * 4 + w] = s2;
            }
        }
    __syncthreads();
    if (t < 32) {
        float sa = red1[t*4] + red1[t*4+1] + red1[t*4+2] + red1[t*4+3];
        float sb = red2[t*4] + red2[t*4+1] + red2[t*4+2] + red2[t*4+3];
        float m = sa * (1.f / 256.f);
        muS[t] = m;
        rrS[t] = rsqrtf(sb * (1.f / 256.f) - m * m + EPSV);
    }
    __syncthreads();   // also: all XT reads done -> Sl reuse safe
    // scatter all quadrants at once (Sl aliases XT)
#pragma unroll
    for (int mi = 0; mi < 2; ++mi)
#pragma unroll
        for (int ni = 0; ni < 4; ++ni)
#pragma unroll
            for (int r = 0; r < 4; ++r)
                Sl[(mi * 16 + quad * 4 + r) * 260 + w * 64 + ni * 16 + lane16] = acc[mi][ni][r];
    __syncthreads();
    {
        const float m = muS[p], rr = rrS[p];
        const long grow = ((long)(b * 1024 + pt * 32 + p)) * 256;
#pragma unroll
        for (int i = 0; i < 8; ++i) {
            const int c = q * 4 + i * 32;
            float4 a  = *(float4*)&Sl[p * 260 + c];
            float4 g4 = *(const float4*)(g + c);
            float4 b4 = *(const float4*)(bt + c);
            float4 o;
            o.x = xv[i].x + fmaxf((a.x - m) * rr * g4.x + b4.x, 0.f);
            o.y = xv[i].y + fmaxf((a.y - m) * rr * g4.y + b4.y, 0.f);
            o.z = xv[i].z + fmaxf((a.z - m) * rr * g4.z + b4.z, 0.f);
            o.w = xv[i].w + fmaxf((a.w - m) * rr * g4.w + b4.w, 0.f);
            *(float4*)(out + grow + c) = o;
        }
    }
}

extern "C" void kernel_launch(void* const* d_in, const int* in_sizes, int n_in,
                              void* d_out, int out_size, void* d_ws, size_t ws_size,
                              hipStream_t stream)
{
    (void)in_sizes; (void)n_in; (void)out_size; (void)ws_size;
    const float* x_feat = (const float*)d_in[0];
    const float* z_feat = (const float*)d_in[1];
    const float* Wz     = (const float*)d_in[2];
    const float* bz     = (const float*)d_in[3];
    const float* Wx     = (const float*)d_in[4];
    const float* bx     = (const float*)d_in[5];
    const float* Wdyn   = (const float*)d_in[6];
    const float* bdyn   = (const float*)d_in[7];
    const float* g_norm = (const float*)d_in[8];
    const float* b_norm = (const float*)d_in[9];
    const float* Wp     = (const float*)d_in[10];
    const float* bp     = (const float*)d_in[11];
    const float* g_ln   = (const float*)d_in[12];
    const float* b_ln   = (const float*)d_in[13];
    float* out = (float*)d_out;

    float* ws       = (float*)d_ws;
    float* Gx       = ws;                    // 4,194,304 f32
    float* Gz       = Gx + 4194304;          // 4,194,304
    float* point    = Gz + 4194304;          // 1,048,576
    float* csx      = point + 1048576;       //    16,384
    float* csz      = csx + 16384;           //    16,384
    float* svec     = csz + 16384;           //    16,384
    unsigned short* MT = (unsigned short*)(svec + 16384);  // 4,194,304 ush

    gram<<<384, 256, 0, stream>>>(x_feat, z_feat, Gx, Gz, csx, csz);
    megamid<<<64, 256, 0, stream>>>(Gx, csx, Wx, bx, Gz, csz, Wz, bz,
                                    Wdyn, bdyn, g_norm, b_norm, Wp, bp,
                                    point, MT, svec);
    final2<<<2048, 256, 0, stream>>>(x_feat, MT, svec, g_ln, b_ln, out);
}

// Round 4
// 280.015 us; speedup vs baseline: 1.2060x; 1.2060x over previous
//
#include <hip/hip_runtime.h>
#include <math.h>

#define EPSV 1e-5f

typedef __attribute__((ext_vector_type(8))) short short8;
typedef __attribute__((ext_vector_type(4))) float f32x4;

// pack two f32 -> two bf16 (RTNE) in one uint
static __device__ __forceinline__ unsigned bfpack2(float lo, float hi) {
    union { float f; unsigned u; } a, b;
    a.f = lo; b.f = hi;
    unsigned ua = a.u + 0x7fffu + ((a.u >> 16) & 1u);
    unsigned ub = b.u + 0x7fffu + ((b.u >> 16) & 1u);
    return (ua >> 16) | (ub & 0xffff0000u);
}
static __device__ __forceinline__ unsigned short bf1(float v) {
    return (unsigned short)bfpack2(v, 0.f);
}

// ---------------------------------------------------------------------------
// K1 gram: G[b] = X_b^T X_b (bf16 output), symmetric 3-tile scheme, 512 thr.
// Grid 384: id = (tile*2+path)*64 + b  (b=id&63 -> XCD affinity).
//   tile 0,1: diag 128x128 (ci=tile); tile 2: off-diag, both mirrors via
//   swapped-operand MFMA (identical fp32 to a transpose).
// Staging: thread owns 4 cols (cq) x 4 p (ph=t>>5, 0..15); XOR-swizzled LDS
// at 16B granularity: slot' = slot ^ ((row>>2)&7) -- kills the 16-way
// transpose-write bank conflict. Reads apply the same swizzle.
// G stored bf16 (same bfpack2 proj would apply -> numerically identical).
// ---------------------------------------------------------------------------
__global__ __launch_bounds__(512) void gram(
    const float* __restrict__ Xx, const float* __restrict__ Xz,
    unsigned short* __restrict__ Gx, unsigned short* __restrict__ Gz,
    float* __restrict__ csx, float* __restrict__ csz)
{
    __shared__ __align__(16) unsigned short AT[128 * 72];
    __shared__ __align__(16) unsigned short BT[128 * 72];
    __shared__ float csr[16 * 128];
    const int id = blockIdx.x;
    const int b = id & 63;
    const int path = (id >> 6) & 1;
    const int tile = id >> 7;            // 0,1: diag; 2: off-diag
    const bool diag = (tile < 2);
    const int ci = diag ? tile : 0;
    const float* X = path ? Xz : Xx;
    unsigned short* G = (path ? Gz : Gx) + (long)b * 65536;
    float* cs = path ? csz : csx;
    const int P = path ? 256 : 1024;
    const int nk = P >> 6;
    const int t = threadIdx.x;
    const int cq = (t & 31) * 4;         // col base within 128-group
    const int ph = t >> 5;               // 0..15, 4 p each
    const int w = t >> 6;                // wave 0..7
    const int quad = (t >> 4) & 3, lane16 = t & 15;
    const float* Xb = X + (long)b * P * 256;
    const int colA = ci * 128;

    f32x4 acc[4][4] = {};
    float csA[4] = {0.f, 0.f, 0.f, 0.f};

    for (int kc = 0; kc < nk; ++kc) {
        const int p0 = kc * 64 + ph * 4;
        float4 va[4], vb[4];
#pragma unroll
        for (int k = 0; k < 4; ++k)
            va[k] = *(const float4*)(Xb + (long)(p0 + k) * 256 + colA + cq);
        if (!diag) {
#pragma unroll
            for (int k = 0; k < 4; ++k)
                vb[k] = *(const float4*)(Xb + (long)(p0 + k) * 256 + 128 + cq);
        }
        __syncthreads();   // previous chunk's MFMA reads done
#pragma unroll
        for (int j = 0; j < 4; ++j) {
            const int row = cq + j;
            const int key = (row >> 2) & 7;
            uint2 pk;
            pk.x = bfpack2(((const float*)&va[0])[j], ((const float*)&va[1])[j]);
            pk.y = bfpack2(((const float*)&va[2])[j], ((const float*)&va[3])[j]);
            *(uint2*)&AT[row * 72 + (((ph >> 1) ^ key) << 3) + ((ph & 1) << 2)] = pk;
            if (diag)
                csA[j] += ((const float*)&va[0])[j] + ((const float*)&va[1])[j]
                        + ((const float*)&va[2])[j] + ((const float*)&va[3])[j];
        }
        if (!diag) {
#pragma unroll
            for (int j = 0; j < 4; ++j) {
                const int row = cq + j;
                const int key = (row >> 2) & 7;
                uint2 pk;
                pk.x = bfpack2(((const float*)&vb[0])[j], ((const float*)&vb[1])[j]);
                pk.y = bfpack2(((const float*)&vb[2])[j], ((const float*)&vb[3])[j]);
                *(uint2*)&BT[row * 72 + (((ph >> 1) ^ key) << 3) + ((ph & 1) << 2)] = pk;
            }
        }
        __syncthreads();
        if (diag) {
            const int wr = w >> 2, wc4 = w & 3;   // 2x4 grid of 64x32 subtiles
#pragma unroll
            for (int ks = 0; ks < 2; ++ks) {
                const int slot = ks * 4 + quad;
                short8 bfr[2];
#pragma unroll
                for (int ni = 0; ni < 2; ++ni) {
                    const int rw = wc4 * 32 + ni * 16 + lane16;
                    bfr[ni] = *(const short8*)&AT[rw * 72 + ((slot ^ ((rw >> 2) & 7)) << 3)];
                }
#pragma unroll
                for (int mi = 0; mi < 4; ++mi) {
                    const int ra = wr * 64 + mi * 16 + lane16;
                    short8 afr = *(const short8*)&AT[ra * 72 + ((slot ^ ((ra >> 2) & 7)) << 3)];
#pragma unroll
                    for (int ni = 0; ni < 2; ++ni)
                        acc[mi][ni] = __builtin_amdgcn_mfma_f32_16x16x32_bf16(afr, bfr[ni], acc[mi][ni], 0, 0, 0);
                }
            }
        } else {
            const int sel = w >> 2, w2 = w & 3, wr = w2 >> 1, wc = w2 & 1;
            const unsigned short* As = sel ? BT : AT;
            const unsigned short* Bs = sel ? AT : BT;
#pragma unroll
            for (int ks = 0; ks < 2; ++ks) {
                const int slot = ks * 4 + quad;
                short8 bfr[4];
#pragma unroll
                for (int ni = 0; ni < 4; ++ni) {
                    const int rw = wc * 64 + ni * 16 + lane16;
                    bfr[ni] = *(const short8*)&Bs[rw * 72 + ((slot ^ ((rw >> 2) & 7)) << 3)];
                }
#pragma unroll
                for (int mi = 0; mi < 4; ++mi) {
                    const int ra = wr * 64 + mi * 16 + lane16;
                    short8 afr = *(const short8*)&As[ra * 72 + ((slot ^ ((ra >> 2) & 7)) << 3)];
#pragma unroll
                    for (int ni = 0; ni < 4; ++ni)
                        acc[mi][ni] = __builtin_amdgcn_mfma_f32_16x16x32_bf16(afr, bfr[ni], acc[mi][ni], 0, 0, 0);
                }
            }
        }
    }
    if (diag) {
        const int wr = w >> 2, wc4 = w & 3;
#pragma unroll
        for (int mi = 0; mi < 4; ++mi) {
            const int rbase = ci * 128 + wr * 64 + mi * 16 + quad * 4;
#pragma unroll
            for (int ni = 0; ni < 2; ++ni) {
                const int col = ci * 128 + wc4 * 32 + ni * 16 + lane16;
#pragma unroll
                for (int r = 0; r < 4; ++r)
                    G[(rbase + r) * 256 + col] = bf1(acc[mi][ni][r]);
            }
        }
#pragma unroll
        for (int j = 0; j < 4; ++j) csr[ph * 128 + cq + j] = csA[j];
        __syncthreads();
        if (t < 128) {
            float s = 0.f;
#pragma unroll
            for (int k = 0; k < 16; ++k) s += csr[k * 128 + t];
            cs[b * 256 + ci * 128 + t] = s;
        }
    } else {
        const int sel = w >> 2, w2 = w & 3, wr = w2 >> 1, wc = w2 & 1;
        const int R = sel ? 128 : 0, C = sel ? 0 : 128;
#pragma unroll
        for (int mi = 0; mi < 4; ++mi) {
            const int rbase = R + wr * 64 + mi * 16 + quad * 4;
#pragma unroll
            for (int ni = 0; ni < 4; ++ni) {
                const int col = C + wc * 64 + ni * 16 + lane16;
#pragma unroll
                for (int r = 0; r < 4; ++r)
                    G[(rbase + r) * 256 + col] = bf1(acc[mi][ni][r]);
            }
        }
    }
}

// ---------------------------------------------------------------------------
// K2 proj: x-path (s<4): kxr = Wx^T Gx + bx(x)csx -> global.
//          z-path (s>=4): kern slice (LDS only) -> dy partials (dy folded in;
//          dy_all kernel deleted). B-fragments read DIRECTLY from bf16 G in
//          global (same-XCD L2) -- no staging, no extra barriers.
// Grid 512: b=id&63, s=id>>6.
// ---------------------------------------------------------------------------
__global__ __launch_bounds__(256) void proj(
    const unsigned short* __restrict__ Gx, const float* __restrict__ csx,
    const float* __restrict__ Wx, const float* __restrict__ bx,
    float* __restrict__ kxr,
    const unsigned short* __restrict__ Gz, const float* __restrict__ csz,
    const float* __restrict__ Wz, const float* __restrict__ bz,
    const float* __restrict__ Wdyn, float* __restrict__ dypart)
{
    __shared__ __align__(16) unsigned short ATW[64 * 264];
    __shared__ float SLICE[64 * 68];
    __shared__ float WC2[64 * 68];
    __shared__ float WD3L[192];
    const int t = threadIdx.x;
    const int id = blockIdx.x;
    const int b = id & 63, s = id >> 6;
    const bool xp = (s < 4);
    const int ct = s & 3;
    const unsigned short* G = xp ? Gx : Gz;
    const float* cs   = xp ? csx : csz;
    const float* W    = xp ? Wx : Wz;
    const float* bias = xp ? bx : bz;
    const int n = t & 63, ph2 = t >> 6;
    // stage W^T -> bf16: ATW[n][c']
#pragma unroll
    for (int cc = 0; cc < 4; ++cc) {
        float v[16];
#pragma unroll
        for (int k = 0; k < 16; ++k) v[k] = W[(ph2 * 64 + cc * 16 + k) * 64 + n];
        uint4 p0, p1;
        p0.x = bfpack2(v[0], v[1]);   p0.y = bfpack2(v[2], v[3]);
        p0.z = bfpack2(v[4], v[5]);   p0.w = bfpack2(v[6], v[7]);
        p1.x = bfpack2(v[8], v[9]);   p1.y = bfpack2(v[10], v[11]);
        p1.z = bfpack2(v[12], v[13]); p1.w = bfpack2(v[14], v[15]);
        *(uint4*)&ATW[n * 264 + ph2 * 64 + cc * 16]     = p0;
        *(uint4*)&ATW[n * 264 + ph2 * 64 + cc * 16 + 8] = p1;
    }
    __syncthreads();
    const int w = t >> 6, quad = (t >> 4) & 3, lane16 = t & 15;
    const unsigned short* Grow =
        G + (long)(b * 256 + ct * 64 + w * 16 + lane16) * 256 + quad * 8;
    short8 bfr[8];
#pragma unroll
    for (int u = 0; u < 8; ++u) bfr[u] = *(const short8*)(Grow + u * 32);
    f32x4 acc[4] = {{0.f,0.f,0.f,0.f},{0.f,0.f,0.f,0.f},{0.f,0.f,0.f,0.f},{0.f,0.f,0.f,0.f}};
#pragma unroll
    for (int kc = 0; kc < 4; ++kc)
#pragma unroll
        for (int ks = 0; ks < 2; ++ks) {
            const int ko = ks * 32 + quad * 8;
            const short8 bfrag = bfr[kc * 2 + ks];
#pragma unroll
            for (int mi = 0; mi < 4; ++mi) {
                short8 afrag = *(const short8*)&ATW[(mi * 16 + lane16) * 264 + kc * 64 + ko];
                acc[mi] = __builtin_amdgcn_mfma_f32_16x16x32_bf16(afrag, bfrag, acc[mi], 0, 0, 0);
            }
        }
    const int col = ct * 64 + w * 16 + lane16;
    const float csv = cs[b * 256 + col];
    if (xp) {
#pragma unroll
        for (int mi = 0; mi < 4; ++mi) {
            const int nrow = mi * 16 + quad * 4;
#pragma unroll
            for (int r = 0; r < 4; ++r)
                kxr[((long)(b * 64 + nrow + r)) * 256 + col] = acc[mi][r] + bias[nrow + r] * csv;
        }
    } else {
        const int cloc = w * 16 + lane16;
#pragma unroll
        for (int mi = 0; mi < 4; ++mi) {
            const int nrow = mi * 16 + quad * 4;
#pragma unroll
            for (int r = 0; r < 4; ++r)
                SLICE[cloc * 68 + nrow + r] = acc[mi][r] + bias[nrow + r] * csv;
        }
        {
            const int m = t & 63, clg = t >> 6;
#pragma unroll
            for (int j = 0; j < 16; ++j) {
                const int cl = clg * 16 + j;
                WC2[cl * 68 + m] = Wdyn[((long)(ct * 64 + cl)) * 67 + 3 + m];
            }
            if (t < 192) WD3L[t] = Wdyn[((long)(ct * 64 + t / 3)) * 67 + (t % 3)];
        }
        __syncthreads();
        const int tr = t >> 4, tc = t & 15;
        float adv[4][4] = {};
#pragma unroll 16
        for (int cl = 0; cl < 64; ++cl) {
            float4 a  = *(float4*)&SLICE[cl * 68 + tr * 4];
            float4 wv = *(float4*)&WC2[cl * 68 + tc * 4];
            adv[0][0]+=a.x*wv.x; adv[0][1]+=a.x*wv.y; adv[0][2]+=a.x*wv.z; adv[0][3]+=a.x*wv.w;
            adv[1][0]+=a.y*wv.x; adv[1][1]+=a.y*wv.y; adv[1][2]+=a.y*wv.z; adv[1][3]+=a.y*wv.w;
            adv[2][0]+=a.z*wv.x; adv[2][1]+=a.z*wv.y; adv[2][2]+=a.z*wv.z; adv[2][3]+=a.z*wv.w;
            adv[3][0]+=a.w*wv.x; adv[3][1]+=a.w*wv.y; adv[3][2]+=a.w*wv.z; adv[3][3]+=a.w*wv.w;
        }
        const long base = (long)(b * 4 + ct) * 64;
#pragma unroll
        for (int i = 0; i < 4; ++i) {
            float4 o = make_float4(adv[i][0], adv[i][1], adv[i][2], adv[i][3]);
            *(float4*)(dypart + (base + tr * 4 + i) * 68 + tc * 4) = o;
        }
        if (t < 192) {
            const int nwd3 = t / 3, jwd3 = t - nwd3 * 3;
            float wdacc = 0.f;
#pragma unroll 16
            for (int cl = 0; cl < 64; ++cl)
                wdacc += SLICE[cl * 68 + nwd3] * WD3L[cl * 3 + jwd3];
            dypart[(base + nwd3) * 68 + 64 + jwd3] = wdacc;
        }
    }
}

// ---------------------------------------------------------------------------
// K3 depthpoint: reduce dy partials (+bias) in the staging phase, then depth
// conv + point GEMM per (batch, 64-channel tile). grid (4, 64).
// ---------------------------------------------------------------------------
__global__ __launch_bounds__(256) void depthpoint(
    const float* __restrict__ dyp, const float* __restrict__ bdyn,
    const float* __restrict__ v,
    const float* __restrict__ g, const float* __restrict__ Wp,
    float* __restrict__ point, float* __restrict__ partials)
{
    __shared__ float smem[13312];
    float* wpT = smem;           // [m][n] stride 68
    float* wd3 = smem + 4352;    // [m][4]
    float* vt  = smem + 4608;    // [m][lc] stride 68
    float* dep = smem + 8960;    // [m][c_loc] stride 68
    float* rs  = vt;             // alias after depth phase

    const int t = threadIdx.x;
    const int b = blockIdx.y, ct = blockIdx.x, c0 = ct * 64;
    const int tr = t >> 4, tc = t & 15;

#pragma unroll
    for (int i = 0; i < 4; ++i) {
        int idx = t + i * 256; int n = idx >> 4, m0 = (idx & 15) * 4;
        float4 a0 = *(const float4*)(dyp + ((long)((b * 4 + 0) * 64 + n)) * 68 + m0);
        float4 a1 = *(const float4*)(dyp + ((long)((b * 4 + 1) * 64 + n)) * 68 + m0);
        float4 a2 = *(const float4*)(dyp + ((long)((b * 4 + 2) * 64 + n)) * 68 + m0);
        float4 a3 = *(const float4*)(dyp + ((long)((b * 4 + 3) * 64 + n)) * 68 + m0);
        float4 w4;
        w4.x = a0.x + a1.x + a2.x + a3.x + bdyn[3 + m0 + 0];
        w4.y = a0.y + a1.y + a2.y + a3.y + bdyn[3 + m0 + 1];
        w4.z = a0.z + a1.z + a2.z + a3.z + bdyn[3 + m0 + 2];
        w4.w = a0.w + a1.w + a2.w + a3.w + bdyn[3 + m0 + 3];
        wpT[(m0+0)*68 + n] = w4.x; wpT[(m0+1)*68 + n] = w4.y;
        wpT[(m0+2)*68 + n] = w4.z; wpT[(m0+3)*68 + n] = w4.w;
    }
    if (t < 64) {
        long o0 = ((long)((b * 4 + 0) * 64 + t)) * 68 + 64;
        long o1 = ((long)((b * 4 + 1) * 64 + t)) * 68 + 64;
        long o2 = ((long)((b * 4 + 2) * 64 + t)) * 68 + 64;
        long o3 = ((long)((b * 4 + 3) * 64 + t)) * 68 + 64;
#pragma unroll
        for (int j = 0; j < 3; ++j)
            wd3[t*4+j] = dyp[o0+j] + dyp[o1+j] + dyp[o2+j] + dyp[o3+j] + bdyn[j];
    }
    {
        int m = t >> 2, lc0 = (t & 3) * 17;
#pragma unroll
        for (int k = 0; k < 17; ++k) {
            int lc = lc0 + k;
            if (lc < 66) {
                int c = c0 - 1 + lc;
                vt[m * 68 + lc] = (c >= 0 && c < 256) ? v[((long)(b * 64 + m)) * 256 + c] : 0.f;
            }
        }
    }
    __syncthreads();
#pragma unroll
    for (int im = 0; im < 4; ++im) {
        int m = tr * 4 + im;
        float w0 = wd3[m*4+0], w1 = wd3[m*4+1], w2 = wd3[m*4+2];
#pragma unroll
        for (int jc = 0; jc < 4; ++jc) {
            int cl = tc * 4 + jc;
            float d = w0 * vt[m*68 + cl] + w1 * vt[m*68 + cl + 1] + w2 * vt[m*68 + cl + 2];
            dep[m*68 + cl] = fmaxf(d, 0.f);
        }
    }
    __syncthreads();
    float acc[4][4] = {};
#pragma unroll 16
    for (int m = 0; m < 64; ++m) {
        float4 a4 = *(float4*)&wpT[m * 68 + tr * 4];
        float4 d4 = *(float4*)&dep[m * 68 + tc * 4];
        acc[0][0]+=a4.x*d4.x; acc[0][1]+=a4.x*d4.y; acc[0][2]+=a4.x*d4.z; acc[0][3]+=a4.x*d4.w;
        acc[1][0]+=a4.y*d4.x; acc[1][1]+=a4.y*d4.y; acc[1][2]+=a4.y*d4.z; acc[1][3]+=a4.y*d4.w;
        acc[2][0]+=a4.z*d4.x; acc[2][1]+=a4.z*d4.y; acc[2][2]+=a4.z*d4.z; acc[2][3]+=a4.z*d4.w;
        acc[3][0]+=a4.w*d4.x; acc[3][1]+=a4.w*d4.y; acc[3][2]+=a4.w*d4.z; acc[3][3]+=a4.w*d4.w;
    }
    int cg = c0 + tc * 4;
    float4 g4  = *(const float4*)(g + cg);
    float4 wp4 = *(const float4*)(Wp + cg);
    float gw0 = g4.x*wp4.x, gw1 = g4.y*wp4.y, gw2 = g4.z*wp4.z, gw3 = g4.w*wp4.w;
#pragma unroll
    for (int i = 0; i < 4; ++i) {
        float4 o = make_float4(acc[i][0], acc[i][1], acc[i][2], acc[i][3]);
        *(float4*)(point + ((long)(b * 64 + tr * 4 + i)) * 256 + cg) = o;
        float s  = o.x + o.y + o.z + o.w;
        float s2 = o.x*o.x + o.y*o.y + o.z*o.z + o.w*o.w;
        float dg = o.x*gw0 + o.y*gw1 + o.z*gw2 + o.w*gw3;
        rs[0*1088 + (tr*4+i)*17 + tc] = s;
        rs[1*1088 + (tr*4+i)*17 + tc] = s2;
        rs[2*1088 + (tr*4+i)*17 + tc] = dg;
    }
    __syncthreads();
    if (t < 64) {
        float s = 0.f, s2 = 0.f, dg = 0.f;
#pragma unroll
        for (int j = 0; j < 16; ++j) {
            s  += rs[t*17 + j];
            s2 += rs[1088 + t*17 + j];
            dg += rs[2176 + t*17 + j];
        }
        long base = ((long)(b * 4 + ct)) * 192;
        partials[base + t]        = s;
        partials[base + 64 + t]   = s2;
        partials[base + 128 + t]  = dg;
    }
}

// ---------------------------------------------------------------------------
// K4 lntem: LN stats + proto (closed form) + tem. (verbatim round-2)
// ---------------------------------------------------------------------------
__global__ __launch_bounds__(256) void lntem(
    const float* __restrict__ partials, const float* __restrict__ point,
    const float* __restrict__ g, const float* __restrict__ bta,
    const float* __restrict__ Wp, const float* __restrict__ bp,
    float* __restrict__ murr, float* __restrict__ AB)
{
    __shared__ float sA[256], sB[256];
    __shared__ float wnv[64];
    __shared__ float tot[4];
    const int b = blockIdx.x, t = threadIdx.x;
    const int c = t;
    float gc = g[c], bc = bta[c], wpc = Wp[c];
    sA[t] = gc * wpc; sB[t] = bc * wpc;
    __syncthreads();
    for (int off = 128; off >= 1; off >>= 1) {
        if (t < off) { sA[t] += sA[t+off]; sB[t] += sB[t+off]; }
        __syncthreads();
    }
    if (t == 0) { tot[0] = sA[0]; tot[1] = sB[0] + bp[0]; }
    __syncthreads();
    float Sgw = tot[0], Sbw = tot[1];

    float protoe = 0.f, mu = 0.f, rr = 0.f;
    if (t < 64) {
        float S1 = 0.f, S2 = 0.f, Sdg = 0.f;
#pragma unroll
        for (int ct = 0; ct < 4; ++ct) {
            long o = ((long)(b * 4 + ct)) * 192;
            S1 += partials[o + t]; S2 += partials[o + 64 + t]; Sdg += partials[o + 128 + t];
        }
        mu = S1 * (1.f / 256.f);
        float var = S2 * (1.f / 256.f) - mu * mu;
        rr = rsqrtf(var + EPSV);
        protoe = rr * (Sdg - mu * Sgw) + Sbw;
        wnv[t] = protoe * rr;
        murr[b * 128 + 2*t]     = rr;
        murr[b * 128 + 2*t + 1] = -mu * rr;
    }
    __syncthreads();
    sA[t] = (t < 64) ? protoe * rr * mu : 0.f;
    sB[t] = (t < 64) ? protoe : 0.f;
    __syncthreads();
    for (int off = 128; off >= 1; off >>= 1) {
        if (t < off) { sA[t] += sA[t+off]; sB[t] += sB[t+off]; }
        __syncthreads();
    }
    if (t == 0) { tot[2] = sA[0]; tot[3] = sB[0]; }
    __syncthreads();
    float Bv = tot[2], Sv = tot[3];

    const float* pcol = point + (long)b * 64 * 256 + c;
    float a0 = 0.f, a1 = 0.f, a2 = 0.f, a3 = 0.f;
#pragma unroll
    for (int n = 0; n < 64; n += 4) {
        a0 += wnv[n+0] * pcol[(n+0) * 256];
        a1 += wnv[n+1] * pcol[(n+1) * 256];
        a2 += wnv[n+2] * pcol[(n+2) * 256];
        a3 += wnv[n+3] * pcol[(n+3) * 256];
    }
    float accA = a0 + a1 + a2 + a3;
    float x = gc * (accA - Bv) + bc * Sv;
    float temv = 1.f / (1.f + expf(-x));
    AB[b * 512 + c]       = gc * temv;
    AB[b * 512 + 256 + c] = bc * temv;
}

// ---------------------------------------------------------------------------
// K5 buildM: (verbatim round-2) kxs -> MT bf16, svec.
// ---------------------------------------------------------------------------
__global__ __launch_bounds__(256) void buildM(
    const float* __restrict__ point, const float* __restrict__ murr,
    const float* __restrict__ AB, const float* __restrict__ Wx,
    const float* __restrict__ bx,
    unsigned short* __restrict__ MT, float* __restrict__ svec)
{
    __shared__ float ks_s[64 * 68];
    __shared__ float wt_s[64 * 68];
    const int t = threadIdx.x;
    const int id = blockIdx.x;
    const int b = id & 63, mt = id >> 6;
    {
        const int n = t >> 2, q = t & 3;
        const float rn = murr[b * 128 + 2 * n], qn = murr[b * 128 + 2 * n + 1];
        const float* prow = point + ((long)(b * 64 + n)) * 256 + mt * 64 + q * 16;
        const float* Arow = AB + b * 512 + mt * 64 + q * 16;
#pragma unroll
        for (int j = 0; j < 4; ++j) {
            float4 p4 = *(const float4*)(prow + j * 4);
            float4 A4 = *(const float4*)(Arow + j * 4);
            float4 B4 = *(const float4*)(Arow + 256 + j * 4);
            float4 kv;
            kv.x = (p4.x * rn + qn) * A4.x + B4.x;
            kv.y = (p4.y * rn + qn) * A4.y + B4.y;
            kv.z = (p4.z * rn + qn) * A4.z + B4.z;
            kv.w = (p4.w * rn + qn) * A4.w + B4.w;
            *(float4*)&ks_s[n * 68 + q * 16 + j * 4] = kv;
        }
    }
    __syncthreads();
    if (t < 64) {
        float sv = 0.f;
#pragma unroll
        for (int n2 = 0; n2 < 64; ++n2) sv += bx[n2] * ks_s[n2 * 68 + t];
        svec[b * 256 + mt * 64 + t] = sv;
    }
    const int tr = t >> 4, tc = t & 15;
    const int nw = t & 63, ph = t >> 6;
    for (int cc = 0; cc < 4; ++cc) {
        float wv[16];
#pragma unroll
        for (int k = 0; k < 16; ++k) wv[k] = Wx[(cc * 64 + ph * 16 + k) * 64 + nw];
        __syncthreads();
#pragma unroll
        for (int k = 0; k < 16; ++k) wt_s[nw * 68 + ph * 16 + k] = wv[k];
        __syncthreads();
        float a2[4][4] = {};
#pragma unroll 16
        for (int n2 = 0; n2 < 64; ++n2) {
            float4 a4 = *(float4*)&ks_s[n2 * 68 + tr * 4];
            float4 w4 = *(float4*)&wt_s[n2 * 68 + tc * 4];
            a2[0][0]+=a4.x*w4.x; a2[0][1]+=a4.x*w4.y; a2[0][2]+=a4.x*w4.z; a2[0][3]+=a4.x*w4.w;
            a2[1][0]+=a4.y*w4.x; a2[1][1]+=a4.y*w4.y; a2[1][2]+=a4.y*w4.z; a2[1][3]+=a4.y*w4.w;
            a2[2][0]+=a4.z*w4.x; a2[2][1]+=a4.z*w4.y; a2[2][2]+=a4.z*w4.z; a2[2][3]+=a4.z*w4.w;
            a2[3][0]+=a4.w*w4.x; a2[3][1]+=a4.w*w4.y; a2[3][2]+=a4.w*w4.z; a2[3][3]+=a4.w*w4.w;
        }
#pragma unroll
        for (int i = 0; i < 4; ++i) {
            uint2 pk;
            pk.x = bfpack2(a2[i][0], a2[i][1]);
            pk.y = bfpack2(a2[i][2], a2[i][3]);
            *(uint2*)&MT[((long)(b * 256 + mt * 64 + tr * 4 + i)) * 256 + cc * 64 + tc * 4] = pk;
        }
    }
}

// ---------------------------------------------------------------------------
// K6 final2: round-2 kernel (18KB LDS, known-good) + ks+1 B-frag software
// prefetch. 32-row tiles, grid 2048, b=id&63 (XCD affinity for MT_b).
// ---------------------------------------------------------------------------
__global__ __launch_bounds__(256) void final2(
    const float* __restrict__ xf, const unsigned short* __restrict__ MT,
    const float* __restrict__ svec, const float* __restrict__ g,
    const float* __restrict__ bt, float* __restrict__ out)
{
    __shared__ __align__(16) float SlArr[32 * 132];
    __shared__ float red1[128], red2[128];
    __shared__ float muS[32], rrS[32];
    unsigned short* XT = (unsigned short*)SlArr;      // [32 p][264 pad] bf16
    float* Sl = SlArr;                                // [32 p][132] f32
    const int t = threadIdx.x;
    const int id = blockIdx.x;
    const int b = id & 63, pt = id >> 6;
    const int w = t >> 6, quad = (t >> 4) & 3, lane16 = t & 15;
    const float* Xb = xf + ((long)(b * 1024 + pt * 32)) * 256;
    {
        const int p = t >> 3, q = t & 7;
#pragma unroll
        for (int i = 0; i < 8; ++i) {
            const int c = q * 32 + i * 4;
            float4 v = *(const float4*)(Xb + (long)p * 256 + c);
            uint2 pk;
            pk.x = bfpack2(v.x, v.y);
            pk.y = bfpack2(v.z, v.w);
            *(uint2*)&XT[p * 264 + c] = pk;
        }
    }
    __syncthreads();
    f32x4 acc[2][4] = {};
    const unsigned short* Mb = MT + (long)b * 65536 + quad * 8;
    short8 bf4[4];
#pragma unroll
    for (int ni = 0; ni < 4; ++ni)
        bf4[ni] = *(const short8*)(Mb + (long)(w * 64 + ni * 16 + lane16) * 256);
    for (int ks = 0; ks < 8; ++ks) {
        const int ko = ks * 32 + quad * 8;
        short8 nbf[4];
        if (ks + 1 < 8) {
#pragma unroll
            for (int ni = 0; ni < 4; ++ni)
                nbf[ni] = *(const short8*)(Mb + (long)(w * 64 + ni * 16 + lane16) * 256 + (ks + 1) * 32);
        }
        short8 af2[2];
#pragma unroll
        for (int mi = 0; mi < 2; ++mi)
            af2[mi] = *(const short8*)&XT[(mi * 16 + lane16) * 264 + ko];
#pragma unroll
        for (int mi = 0; mi < 2; ++mi)
#pragma unroll
            for (int ni = 0; ni < 4; ++ni)
                acc[mi][ni] = __builtin_amdgcn_mfma_f32_16x16x32_bf16(af2[mi], bf4[ni], acc[mi][ni], 0, 0, 0);
#pragma unroll
        for (int ni = 0; ni < 4; ++ni) bf4[ni] = nbf[ni];
    }
    float sv4[4];
#pragma unroll
    for (int ni = 0; ni < 4; ++ni) sv4[ni] = svec[b * 256 + w * 64 + ni * 16 + lane16];
#pragma unroll
    for (int mi = 0; mi < 2; ++mi)
#pragma unroll
        for (int r = 0; r < 4; ++r) {
            float s1 = 0.f, s2 = 0.f;
#pragma unroll
            for (int ni = 0; ni < 4; ++ni) {
                float v2 = acc[mi][ni][r] + sv4[ni];
                acc[mi][ni][r] = v2;
                s1 += v2; s2 += v2 * v2;
            }
#pragma unroll
            for (int m = 1; m <= 8; m <<= 1) {
                s1 += __shfl_xor(s1, m);
                s2 += __shfl_xor(s2, m);
            }
            if (lane16 == 0) {
                red1[(mi * 16 + quad * 4 + r) * 4 + w] = s1;
                red2[(mi * 16 + quad * 4 + r) * 4 + w] = s2;
            }
        }
    __syncthreads();
    if (t < 32) {
        float sa = red1[t*4] + red1[t*4+1] + red1[t*4+2] + red1[t*4+3];
        float sb = red2[t*4] + red2[t*4+1] + red2[t*4+2] + red2[t*4+3];
        float m = sa * (1.f / 256.f);
        muS[t] = m;
        rrS[t] = rsqrtf(sb * (1.f / 256.f) - m * m + EPSV);
    }
#pragma unroll
    for (int h = 0; h < 2; ++h) {
        __syncthreads();
        if ((w >> 1) == h) {
            const int chalf = (w & 1) * 64;
#pragma unroll
            for (int mi = 0; mi < 2; ++mi)
#pragma unroll
                for (int ni = 0; ni < 4; ++ni)
#pragma unroll
                    for (int r = 0; r < 4; ++r)
                        Sl[(mi * 16 + quad * 4 + r) * 132 + chalf + ni * 16 + lane16] = acc[mi][ni][r];
        }
        __syncthreads();
        {
            const int p = t >> 3, q = t & 7;
            const float m = muS[p], rr = rrS[p];
            const long grow = ((long)(b * 1024 + pt * 32 + p)) * 256;
#pragma unroll
            for (int j = 0; j < 4; ++j) {
                const int cl = q * 16 + j * 4;
                const int c = h * 128 + cl;
                float4 a  = *(float4*)&Sl[p * 132 + cl];
                float4 g4 = *(const float4*)(g + c);
                float4 b4 = *(const float4*)(bt + c);
                float4 xv = *(const float4*)(xf + grow + c);
                float4 o;
                o.x = xv.x + fmaxf((a.x - m) * rr * g4.x + b4.x, 0.f);
                o.y = xv.y + fmaxf((a.y - m) * rr * g4.y + b4.y, 0.f);
                o.z = xv.z + fmaxf((a.z - m) * rr * g4.z + b4.z, 0.f);
                o.w = xv.w + fmaxf((a.w - m) * rr * g4.w + b4.w, 0.f);
                *(float4*)(out + grow + c) = o;
            }
        }
    }
}

extern "C" void kernel_launch(void* const* d_in, const int* in_sizes, int n_in,
                              void* d_out, int out_size, void* d_ws, size_t ws_size,
                              hipStream_t stream)
{
    (void)in_sizes; (void)n_in; (void)out_size; (void)ws_size;
    const float* x_feat = (const float*)d_in[0];
    const float* z_feat = (const float*)d_in[1];
    const float* Wz     = (const float*)d_in[2];
    const float* bz     = (const float*)d_in[3];
    const float* Wx     = (const float*)d_in[4];
    const float* bx     = (const float*)d_in[5];
    const float* Wdyn   = (const float*)d_in[6];
    const float* bdyn   = (const float*)d_in[7];
    const float* g_norm = (const float*)d_in[8];
    const float* b_norm = (const float*)d_in[9];
    const float* Wp     = (const float*)d_in[10];
    const float* bp     = (const float*)d_in[11];
    const float* g_ln   = (const float*)d_in[12];
    const float* b_ln   = (const float*)d_in[13];
    float* out = (float*)d_out;

    float* ws       = (float*)d_ws;
    float* kxr      = ws;                    // 1,048,576 f32
    float* point    = kxr + 1048576;         // 1,048,576
    float* dypart   = point + 1048576;       // 1,114,112
    float* partials = dypart + 1114112;      //    49,152
    float* murr     = partials + 49152;      //     8,192
    float* AB       = murr + 8192;           //    32,768
    float* csx      = AB + 32768;            //    16,384
    float* csz      = csx + 16384;           //    16,384
    float* svec     = csz + 16384;           //    16,384
    unsigned short* Gx = (unsigned short*)(svec + 16384);  // 4,194,304 ush
    unsigned short* Gz = Gx + 4194304;                     // 4,194,304
    unsigned short* MT = Gz + 4194304;                     // 4,194,304

    gram<<<384, 512, 0, stream>>>(x_feat, z_feat, Gx, Gz, csx, csz);
    proj<<<512, 256, 0, stream>>>(Gx, csx, Wx, bx, kxr, Gz, csz, Wz, bz,
                                  Wdyn, dypart);
    depthpoint<<<dim3(4, 64), 256, 0, stream>>>(dypart, bdyn, kxr, g_norm, Wp,
                                                point, partials);
    lntem<<<64, 256, 0, stream>>>(partials, point, g_norm, b_norm, Wp, bp, murr, AB);
    buildM<<<256, 256, 0, stream>>>(point, murr, AB, Wx, bx, MT, svec);
    final2<<<2048, 256, 0, stream>>>(x_feat, MT, svec, g_ln, b_ln, out);
}